// Round 14
// baseline (790.279 us; speedup 1.0000x reference)
//
#include <hip/hip_runtime.h>

#define E_DIM  256
#define N_E    16384
#define N_ROWS 8192
#define HW     1024
#define NPART  128          // n-tiles of 128 cols

typedef _Float16 f16x8 __attribute__((ext_vector_type(8)));
typedef float    f32x4 __attribute__((ext_vector_type(4)));

#define ESCALE   1048576.0f          // 2^20 (exact)
#define UNSCALE  1.9073486328125e-6f // 2^-19: acc*2^-19 == 2*dot (approx, single limb)

// DPP row_ror:N over 16-lane rows (= our tx reduce group). Pure VALU.
#define ROR_DPP(v, CTRL) \
  ((unsigned)__builtin_amdgcn_update_dpp(0, (int)(v), (CTRL), 0xF, 0xF, false))

// reference-semantics f32 score: fl32(fl32(zn+en) - fl32(2*dot)).
// All dot intermediates are ~1e-4 scale (|e|<6.1e-5): f32 sum error ~1e-9 <<
// final-subtraction ulp 3e-5 -> same f32 bucket as numpy's einsum.
__device__ __forceinline__ float score_ref32(const float* zr,
                                             const float* __restrict__ E,
                                             const float* __restrict__ eNorm,
                                             int idx, float zn) {
  const float4* e4p = (const float4*)(E + (size_t)idx * E_DIM);
  float d0 = 0.f, d1 = 0.f, d2 = 0.f, d3 = 0.f;
#pragma unroll 16
  for (int q = 0; q < 64; ++q) {
    float4 e4 = e4p[q];
    d0 = fmaf(zr[q * 4 + 0], e4.x, d0);
    d1 = fmaf(zr[q * 4 + 1], e4.y, d1);
    d2 = fmaf(zr[q * 4 + 2], e4.z, d2);
    d3 = fmaf(zr[q * 4 + 3], e4.w, d3);
  }
  float dot = (d0 + d1) + (d2 + d3);
  float base = zn + eNorm[idx];   // f32 add, matches np broadcast add
  float td = 2.0f * dot;          // exact (power of 2)
  return base - td;               // f32 final rounding at the reference ulp
}

// ---------- fused prep: single-limb A/B + eNorm + numpy-exact zNorm + z L1 ----------
#define ZB_Z    256
#define EB_E    512
__global__ __launch_bounds__(256) void k_prep(const float* __restrict__ z,
                                              const float* __restrict__ E,
                                              _Float16* __restrict__ Ah,
                                              _Float16* __restrict__ Bh,
                                              float* __restrict__ eNorm,
                                              float* __restrict__ zNorm,
                                              float* __restrict__ zL1,
                                              float* __restrict__ out_loss) {
#pragma clang fp contract(off)
  const int bi = blockIdx.x, t = threadIdx.x;

  if (bi < ZB_Z) {
    // ---- z section: 32-row tile ----
    __shared__ float sLZ[256][32];   // 32 KB z tile [channel][row]
    __shared__ float sN2[16][32];    // square-chain partials [c16][row]
    __shared__ float sL1[16][32];    // abs-chain partials
    const int n0 = bi * 32;
    const int b = n0 >> 10, hw0 = n0 & 1023;

    {
      const int nl = t & 31, cs = t >> 5;
      const float* zb = z + (size_t)b * E_DIM * HW + hw0 + nl;
#pragma unroll 4
      for (int it = 0; it < 32; ++it) {
        int c = it * 8 + cs;
        sLZ[c][nl] = zb[(size_t)c * HW];
      }
    }
    __syncthreads();

    // phase L: high limb only. thread = (row nl, segment seg = kc)
    {
      const int nl = t & 31, seg = t >> 5;
      const int n = n0 + nl;
      const int perm = (n >> 1) & 3;
#pragma unroll
      for (int u = 0; u < 4; ++u) {
        const int c0 = seg * 32 + u * 8;
        f16x8 hh;
#pragma unroll
        for (int j = 0; j < 8; ++j) hh[j] = (_Float16)sLZ[c0 + j][nl];
        size_t dst = (size_t)seg * (N_ROWS * 32) + (size_t)n * 32 + (size_t)(u ^ perm) * 8;
        *(f16x8*)&Ah[dst] = hh;
      }
    }

    // phase N: numpy-exact square chains (zNorm) + abs chains (zL1 window scale)
#pragma unroll
    for (int it = 0; it < 2; ++it) {
      int task = it * 256 + t;
      int nl = task & 31, c16 = task >> 5;
      int h = c16 >> 3, j = c16 & 7;
      float r2 = 0.f, r1 = 0.f;
#pragma unroll
      for (int i = 0; i < 16; ++i) {
        float v = sLZ[h * 128 + i * 8 + j][nl];
        r2 = r2 + v * v;
        r1 = r1 + fabsf(v);
      }
      sN2[c16][nl] = r2;
      sL1[c16][nl] = r1;
    }
    __syncthreads();
    if (t < 32) {
      float q[16], p[16];
#pragma unroll
      for (int c16 = 0; c16 < 16; ++c16) { q[c16] = sN2[c16][t]; p[c16] = sL1[c16][t]; }
      float h0 = ((q[0] + q[1]) + (q[2] + q[3])) + ((q[4] + q[5]) + (q[6] + q[7]));
      float h1 = ((q[8] + q[9]) + (q[10] + q[11])) + ((q[12] + q[13]) + (q[14] + q[15]));
      zNorm[n0 + t] = h0 + h1;
      float g0 = ((p[0] + p[1]) + (p[2] + p[3])) + ((p[4] + p[5]) + (p[6] + p[7]));
      float g1 = ((p[8] + p[9]) + (p[10] + p[11])) + ((p[12] + p[13]) + (p[14] + p[15]));
      zL1[n0 + t] = g0 + g1;
    }
  } else {
    // ---- E section ----
    __shared__ float sNP[8][32];
    const int be = bi - ZB_Z;
    if (be == 0 && t == 0) out_loss[0] = 0.f;
    const int kc = t >> 5, rl = t & 31;
    const int k = be * 32 + rl;
    const int perm = (k >> 1) & 3;
    const float* src = E + (size_t)k * E_DIM + kc * 32;

    float4 v4[8];
#pragma unroll
    for (int u2 = 0; u2 < 8; ++u2) v4[u2] = ((const float4*)src)[u2];

    float nsum = 0.f;
    size_t base = (size_t)kc * (N_E * 32) + (size_t)k * 32;
#pragma unroll
    for (int u = 0; u < 4; ++u) {
      float v[8] = {v4[u * 2].x, v4[u * 2].y, v4[u * 2].z, v4[u * 2].w,
                    v4[u * 2 + 1].x, v4[u * 2 + 1].y, v4[u * 2 + 1].z, v4[u * 2 + 1].w};
      f16x8 hh;
#pragma unroll
      for (int j = 0; j < 8; ++j) {
        nsum = nsum + v[j] * v[j];
        hh[j] = (_Float16)(v[j] * ESCALE);
      }
      *(f16x8*)&Bh[base + (size_t)(u ^ perm) * 8] = hh;
    }
    sNP[kc][rl] = nsum;
    __syncthreads();
    if (t < 32) {
      float s = 0.f;
#pragma unroll
      for (int kc2 = 0; kc2 < 8; ++kc2) s += sNP[kc2][t];
      eNorm[be * 32 + t] = s;
    }
  }
}

// ---------- main: R26 — R25 wave geometry (64 rows x 128 cols/wave, direct-L2,
// zero LDS/barriers) repackaged as 4-wave 256-thread blocks (BM=256) with
// __launch_bounds__(256,4): 4 waves/SIMD admissible at VGPR<=128 -> phase
// diversity lets the epilogue VALU of some waves overlap other waves' MFMA.
__global__ __launch_bounds__(256, 4) void k_scores_mfma(
    const _Float16* __restrict__ Ah, const _Float16* __restrict__ Bh,
    const float* __restrict__ eNorm,
    unsigned* __restrict__ pK1, unsigned* __restrict__ pK2,
    unsigned* __restrict__ pK3) {
#pragma clang fp contract(off)
  const int mt = blockIdx.x, nt = blockIdx.y;
  const int m0 = mt * 256, n0 = nt * 128;

  const int t = threadIdx.x;
  const int lane = t & 63, w = t >> 6;        // 4 waves
  const int tx = lane & 15, quad = lane >> 4;
  const int wm = w * 64;                      // wave rows [wm, wm+64), cols [0,128)
  const int swz = (quad ^ ((tx >> 1) & 3)) * 8;  // physical f16 offset of logical block

  const size_t planeA = (size_t)N_ROWS * 32, planeB = (size_t)N_E * 32;
  const size_t baseA = (size_t)(m0 + wm + tx) * 32 + swz;   // f16 index
  const size_t baseB = (size_t)(n0 + tx) * 32 + swz;

  f32x4 acc[4][8];
#pragma unroll
  for (int i = 0; i < 4; ++i)
#pragma unroll
    for (int j = 0; j < 8; ++j) acc[i][j] = (f32x4){0.f, 0.f, 0.f, 0.f};

#pragma unroll
  for (int kc = 0; kc < 8; ++kc) {
    f16x8 ah[4], bh[8];
#pragma unroll
    for (int i = 0; i < 4; ++i)
      ah[i] = *(const f16x8*)&Ah[kc * planeA + baseA + (size_t)i * 512];
#pragma unroll
    for (int j = 0; j < 8; ++j)
      bh[j] = *(const f16x8*)&Bh[kc * planeB + baseB + (size_t)j * 512];

    __builtin_amdgcn_s_setprio(1);
#pragma unroll
    for (int j = 0; j < 8; ++j)
#pragma unroll
      for (int i = 0; i < 4; ++i)
        acc[i][j] = __builtin_amdgcn_mfma_f32_16x16x32_f16(ah[i], bh[j], acc[i][j], 0, 0, 0);
    __builtin_amdgcn_s_setprio(0);
  }

  // ---- epilogue: packed-key top-3 per (row, 128-col tile), DPP merge ----
  // eNq in registers (same fmaf as before -> bit-identical keys)
  float enq[8];
#pragma unroll
  for (int j = 0; j < 8; ++j)
    enq[j] = fmaf(eNorm[n0 + j * 16 + tx], 2097152.f, 131072.f);

#pragma unroll
  for (int i = 0; i < 4; ++i) {
#pragma unroll
    for (int r = 0; r < 4; ++r) {
      const int rloc = wm + i * 16 + quad * 4 + r;
      unsigned k[8];
#pragma unroll
      for (int j = 0; j < 8; ++j) {
        float tq = fmaf(acc[i][j][r], -4.0f, enq[j]);   // (s - SMIN)*2^21
        k[j] = (((unsigned)tq) << 14) | (unsigned)(n0 + j * 16 + tx);
      }
      // top-3 of 8 = two top-3-of-4 networks + sorted-triple merge
      unsigned a = min(k[0], k[1]), b = max(k[0], k[1]);
      unsigned c = min(k[2], k[3]), d = max(k[2], k[3]);
      unsigned a1 = min(a, c), e0 = max(a, c), f0 = min(b, d);
      unsigned a2 = min(e0, f0), a3 = max(e0, f0);
      a = min(k[4], k[5]); b = max(k[4], k[5]);
      c = min(k[6], k[7]); d = max(k[6], k[7]);
      unsigned b1 = min(a, c); e0 = max(a, c); f0 = min(b, d);
      unsigned b2 = min(e0, f0), b3 = max(e0, f0);
      unsigned m1 = min(a1, b1);
      unsigned m2 = min(max(a1, b1), min(a2, b2));
      unsigned m3 = min(min(a3, b3), min(max(a2, b1), max(a1, b2)));
      // 4-round row_ror DPP merge of sorted triples (windows partition exactly)
#define MERGE_R(CTRL)                                              \
      {                                                            \
        unsigned o1 = ROR_DPP(m1, CTRL);                           \
        unsigned o2 = ROR_DPP(m2, CTRL);                           \
        unsigned o3 = ROR_DPP(m3, CTRL);                           \
        unsigned n1 = min(m1, o1);                                 \
        unsigned n2 = min(max(m1, o1), min(m2, o2));               \
        unsigned n3 = min(min(m3, o3), min(max(m2, o1), max(m1, o2))); \
        m1 = n1; m2 = n2; m3 = n3;                                 \
      }
      MERGE_R(0x121)   // ror:1
      MERGE_R(0x122)   // ror:2
      MERGE_R(0x124)   // ror:4
      MERGE_R(0x128)   // ror:8
#undef MERGE_R
      if (tx == 0) {
        const size_t o = (size_t)nt * N_ROWS + m0 + rloc;
        pK1[o] = m1;
        pK2[o] = m2;
        pK3[o] = m3;
      }
    }
  }
}

// ---------- fused post: R23 (1024 threads) — verbatim ----------
__global__ __launch_bounds__(1024) void k_post(
    const unsigned* __restrict__ pK1, const unsigned* __restrict__ pK2,
    const unsigned* __restrict__ pK3,
    const float* __restrict__ zL1, const float* __restrict__ zNorm,
    const float* __restrict__ z, const float* __restrict__ E,
    const float* __restrict__ eNorm,
    float* __restrict__ out, float* __restrict__ out_loss,
    float* __restrict__ out_idx) {
#pragma clang fp contract(off)
  __shared__ float zc[32][264];     // z rows cache (+pad)
  __shared__ unsigned sM[32][32];   // [s][r]
  __shared__ unsigned gK[32];
  __shared__ int   fI[32];
  __shared__ int   cand[32][16];
  __shared__ int   ccnt[32];
  __shared__ int   heavy[32][4];
  __shared__ int   hcnt[32];
  __shared__ float fS[32][32];      // [r][s]
  __shared__ int   fiS[32][32];
  __shared__ float wsum[16];

  const int t = threadIdx.x;
  const int r = t & 31, s = t >> 5;   // s in [0,32)
  const int n0 = blockIdx.x * 32;
  const int n = n0 + r;
  const int b = n >> 10, hw = n & 1023;

  if (t < 32) { ccnt[t] = 0; hcnt[t] = 0; }

  // cache this row's z: thread owns channels [s*8, s*8+8)
  {
    const float* zrow = z + ((size_t)b * E_DIM + s * 8) * HW + hw;
#pragma unroll
    for (int k = 0; k < 8; ++k) zc[r][s * 8 + k] = zrow[(size_t)k * HW];
  }

  // (A) global approx min over 128 tiles: 4 per s-thread
  unsigned mk = 0xFFFFFFFFu;
#pragma unroll
  for (int i = 0; i < 4; ++i) {
    int ti = s * 4 + i;
    mk = min(mk, pK1[(size_t)ti * N_ROWS + n]);
  }
  sM[s][r] = mk;
  __syncthreads();
  if (t < 32) {
    unsigned bk = sM[0][t];
#pragma unroll
    for (int s3 = 1; s3 < 32; ++s3) bk = min(bk, sM[s3][t]);
    gK[t] = bk;
  }
  __syncthreads();

  // (B) window in key space: W = 2^-22*||z||_1 + 8e-5, +3 quant steps slack.
  // k1,k2 in window -> direct candidates (idx packed); k3 in window -> heavy.
  {
    const unsigned qW =
        (unsigned)(fmaf(zL1[n], 2.384185791015625e-7f, 8e-5f) * 2097152.f) + 3u;
    unsigned thrq = (gK[r] >> 14) + qW;
    if (thrq > 262143u) thrq = 262143u;
    const unsigned thrk = (thrq << 14) | 0x3FFFu;
#pragma unroll
    for (int i = 0; i < 4; ++i) {
      int ti = s * 4 + i;
      size_t o = (size_t)ti * N_ROWS + n;
      unsigned k1 = pK1[o], k2 = pK2[o], k3 = pK3[o];
      if (k1 <= thrk) { int p = atomicAdd(&ccnt[r], 1); if (p < 16) cand[r][p] = (int)(k1 & 0x3FFFu); }
      if (k2 <= thrk) { int p = atomicAdd(&ccnt[r], 1); if (p < 16) cand[r][p] = (int)(k2 & 0x3FFFu); }
      if (k3 <= thrk) { int p = atomicAdd(&hcnt[r], 1); if (p < 4)  heavy[r][p] = ti; }
    }
  }
  __syncthreads();

  // (C) f32 reference rescore of window members; lexicographic (s_p, idx) min
  {
    const int rcnt = ccnt[r], rhc = hcnt[r];
    const bool ovf = (rcnt > 16) || (rhc > 4);
    const bool ex = (rcnt > 1) || (rhc > 0);
    float bv = 3.4e38f;
    int bi = 0x7fffffff;
    if (ex) {
      const float zn = zNorm[n];
      if (ovf) {
        for (int k = s; k < N_E; k += 32) {
          float sp = score_ref32(&zc[r][0], E, eNorm, k, zn);
          if (sp < bv || (sp == bv && k < bi)) { bv = sp; bi = k; }
        }
      } else {
        for (int c = s; c < rcnt; c += 32) {
          int idx = cand[r][c];
          float sp = score_ref32(&zc[r][0], E, eNorm, idx, zn);
          if (sp < bv || (sp == bv && idx < bi)) { bv = sp; bi = idx; }
        }
        for (int h = 0; h < rhc; ++h) {
          int ti = heavy[r][h];
          for (int cc = s; cc < 128; cc += 32) {
            int idx = ti * 128 + cc;
            float sp = score_ref32(&zc[r][0], E, eNorm, idx, zn);
            if (sp < bv || (sp == bv && idx < bi)) { bv = sp; bi = idx; }
          }
        }
      }
    }
    fS[r][s] = bv;
    fiS[r][s] = bi;
  }
  __syncthreads();
  if (t < 32) {
    const int rcnt = ccnt[t], rhc = hcnt[t];
    int fidx;
    if (rcnt <= 1 && rhc == 0) {
      fidx = (int)(gK[t] & 0x3FFFu);   // sole window member == unique f32 argmin
    } else {
      float bv = fS[t][0];
      int bi = fiS[t][0];
#pragma unroll
      for (int s3 = 1; s3 < 32; ++s3) {
        float v = fS[t][s3];
        int id = fiS[t][s3];
        if (v < bv || (v == bv && id < bi)) { bv = v; bi = id; }
      }
      fidx = bi;
    }
    fI[t] = fidx;
    out_idx[n0 + t] = (float)fidx;
  }
  __syncthreads();

  // (D) gather + write + loss: thread owns 8 channels [s*8, s*8+8)
  const int idx = fI[r];
  const float4* erow4 = (const float4*)(E + (size_t)idx * E_DIM + s * 8);
  float* orow = out + ((size_t)b * E_DIM + s * 8) * HW + hw;
  float acc = 0.f;
#pragma unroll
  for (int c4 = 0; c4 < 2; ++c4) {
    float4 e4 = erow4[c4];
    float ev[4] = {e4.x, e4.y, e4.z, e4.w};
#pragma unroll
    for (int j2 = 0; j2 < 4; ++j2) {
      int c = c4 * 4 + j2;
      float zv = zc[r][s * 8 + c];
      orow[(size_t)c * HW] = ev[j2];
      float d = ev[j2] - zv;
      acc = fmaf(d, d, acc);
    }
  }
  for (int off = 32; off > 0; off >>= 1) acc += __shfl_down(acc, off, 64);
  if ((t & 63) == 0) wsum[t >> 6] = acc;
  __syncthreads();
  if (t == 0) {
    float s0 = 0.f;
#pragma unroll
    for (int wv = 0; wv < 16; ++wv) s0 += wsum[wv];
    atomicAdd(out_loss, s0 * (1.25f / 2097152.f));
  }
}

extern "C" void kernel_launch(void* const* d_in, const int* in_sizes, int n_in,
                              void* d_out, int out_size, void* d_ws, size_t ws_size,
                              hipStream_t stream) {
  const float* z = (const float*)d_in[0];
  const float* E = (const float*)d_in[1];
  float* out = (float*)d_out;
  float* out_loss = out + 2097152;  // after z_q (8*256*32*32)
  float* out_idx = out + 2097153;

  // workspace (~25 MB): Ah f16[8][8192][32], Bh f16[8][16384][32],
  //                     eNorm, zL1, zNorm, pK1|pK2|pK3 u32[128][8192]
  _Float16* Ah = (_Float16*)d_ws;
  _Float16* Bh = Ah + (size_t)N_ROWS * E_DIM;
  float* eNorm = (float*)(Bh + (size_t)N_E * E_DIM);
  float* zL1 = eNorm + N_E;
  float* zNorm = zL1 + N_ROWS;
  unsigned* pK1 = (unsigned*)(zNorm + N_ROWS);
  unsigned* pK2 = pK1 + (size_t)NPART * N_ROWS;
  unsigned* pK3 = pK2 + (size_t)NPART * N_ROWS;

  k_prep<<<ZB_Z + EB_E, 256, 0, stream>>>(z, E, Ah, Bh, eNorm, zNorm, zL1, out_loss);
  k_scores_mfma<<<dim3(N_ROWS / 256, N_E / 128), 256, 0, stream>>>(
      Ah, Bh, eNorm, pK1, pK2, pK3);
  k_post<<<N_ROWS / 32, 1024, 0, stream>>>(
      pK1, pK2, pK3, zL1, zNorm, z, E, eNorm, out, out_loss, out_idx);
}

// Round 15
// 196.375 us; speedup vs baseline: 4.0243x; 4.0243x over previous
//
#include <hip/hip_runtime.h>

#define E_DIM  256
#define N_E    16384
#define N_ROWS 8192
#define HW     1024
#define NPART  128          // n-tiles of 128 cols

typedef _Float16 f16x8 __attribute__((ext_vector_type(8)));
typedef float    f32x4 __attribute__((ext_vector_type(4)));

#define ESCALE   1048576.0f          // 2^20 (exact)
#define UNSCALE  1.9073486328125e-6f // 2^-19: acc*2^-19 == 2*dot (approx, single limb)

// DPP row_ror:N over 16-lane rows (= our tx reduce group). Pure VALU.
#define ROR_DPP(v, CTRL) \
  ((unsigned)__builtin_amdgcn_update_dpp(0, (int)(v), (CTRL), 0xF, 0xF, false))

// reference-semantics f32 score: fl32(fl32(zn+en) - fl32(2*dot)).
// All dot intermediates are ~1e-4 scale (|e|<6.1e-5): f32 sum error ~1e-9 <<
// final-subtraction ulp 3e-5 -> same f32 bucket as numpy's einsum.
__device__ __forceinline__ float score_ref32(const float* zr,
                                             const float* __restrict__ E,
                                             const float* __restrict__ eNorm,
                                             int idx, float zn) {
  const float4* e4p = (const float4*)(E + (size_t)idx * E_DIM);
  float d0 = 0.f, d1 = 0.f, d2 = 0.f, d3 = 0.f;
#pragma unroll 16
  for (int q = 0; q < 64; ++q) {
    float4 e4 = e4p[q];
    d0 = fmaf(zr[q * 4 + 0], e4.x, d0);
    d1 = fmaf(zr[q * 4 + 1], e4.y, d1);
    d2 = fmaf(zr[q * 4 + 2], e4.z, d2);
    d3 = fmaf(zr[q * 4 + 3], e4.w, d3);
  }
  float dot = (d0 + d1) + (d2 + d3);
  float base = zn + eNorm[idx];   // f32 add, matches np broadcast add
  float td = 2.0f * dot;          // exact (power of 2)
  return base - td;               // f32 final rounding at the reference ulp
}

// ---------- fused prep: single-limb A/B + eNorm + numpy-exact zNorm + z L1 ----------
#define ZB_Z    256
#define EB_E    512
__global__ __launch_bounds__(256) void k_prep(const float* __restrict__ z,
                                              const float* __restrict__ E,
                                              _Float16* __restrict__ Ah,
                                              _Float16* __restrict__ Bh,
                                              float* __restrict__ eNorm,
                                              float* __restrict__ zNorm,
                                              float* __restrict__ zL1,
                                              float* __restrict__ out_loss) {
#pragma clang fp contract(off)
  const int bi = blockIdx.x, t = threadIdx.x;

  if (bi < ZB_Z) {
    // ---- z section: 32-row tile ----
    __shared__ float sLZ[256][32];   // 32 KB z tile [channel][row]
    __shared__ float sN2[16][32];    // square-chain partials [c16][row]
    __shared__ float sL1[16][32];    // abs-chain partials
    const int n0 = bi * 32;
    const int b = n0 >> 10, hw0 = n0 & 1023;

    {
      const int nl = t & 31, cs = t >> 5;
      const float* zb = z + (size_t)b * E_DIM * HW + hw0 + nl;
#pragma unroll 4
      for (int it = 0; it < 32; ++it) {
        int c = it * 8 + cs;
        sLZ[c][nl] = zb[(size_t)c * HW];
      }
    }
    __syncthreads();

    // phase L: high limb only. thread = (row nl, segment seg = kc)
    {
      const int nl = t & 31, seg = t >> 5;
      const int n = n0 + nl;
      const int perm = (n >> 1) & 3;
#pragma unroll
      for (int u = 0; u < 4; ++u) {
        const int c0 = seg * 32 + u * 8;
        f16x8 hh;
#pragma unroll
        for (int j = 0; j < 8; ++j) hh[j] = (_Float16)sLZ[c0 + j][nl];
        size_t dst = (size_t)seg * (N_ROWS * 32) + (size_t)n * 32 + (size_t)(u ^ perm) * 8;
        *(f16x8*)&Ah[dst] = hh;
      }
    }

    // phase N: numpy-exact square chains (zNorm) + abs chains (zL1 window scale)
#pragma unroll
    for (int it = 0; it < 2; ++it) {
      int task = it * 256 + t;
      int nl = task & 31, c16 = task >> 5;
      int h = c16 >> 3, j = c16 & 7;
      float r2 = 0.f, r1 = 0.f;
#pragma unroll
      for (int i = 0; i < 16; ++i) {
        float v = sLZ[h * 128 + i * 8 + j][nl];
        r2 = r2 + v * v;
        r1 = r1 + fabsf(v);
      }
      sN2[c16][nl] = r2;
      sL1[c16][nl] = r1;
    }
    __syncthreads();
    if (t < 32) {
      float q[16], p[16];
#pragma unroll
      for (int c16 = 0; c16 < 16; ++c16) { q[c16] = sN2[c16][t]; p[c16] = sL1[c16][t]; }
      float h0 = ((q[0] + q[1]) + (q[2] + q[3])) + ((q[4] + q[5]) + (q[6] + q[7]));
      float h1 = ((q[8] + q[9]) + (q[10] + q[11])) + ((q[12] + q[13]) + (q[14] + q[15]));
      zNorm[n0 + t] = h0 + h1;
      float g0 = ((p[0] + p[1]) + (p[2] + p[3])) + ((p[4] + p[5]) + (p[6] + p[7]));
      float g1 = ((p[8] + p[9]) + (p[10] + p[11])) + ((p[12] + p[13]) + (p[14] + p[15]));
      zL1[n0 + t] = g0 + g1;
    }
  } else {
    // ---- E section ----
    __shared__ float sNP[8][32];
    const int be = bi - ZB_Z;
    if (be == 0 && t == 0) out_loss[0] = 0.f;
    const int kc = t >> 5, rl = t & 31;
    const int k = be * 32 + rl;
    const int perm = (k >> 1) & 3;
    const float* src = E + (size_t)k * E_DIM + kc * 32;

    float4 v4[8];
#pragma unroll
    for (int u2 = 0; u2 < 8; ++u2) v4[u2] = ((const float4*)src)[u2];

    float nsum = 0.f;
    size_t base = (size_t)kc * (N_E * 32) + (size_t)k * 32;
#pragma unroll
    for (int u = 0; u < 4; ++u) {
      float v[8] = {v4[u * 2].x, v4[u * 2].y, v4[u * 2].z, v4[u * 2].w,
                    v4[u * 2 + 1].x, v4[u * 2 + 1].y, v4[u * 2 + 1].z, v4[u * 2 + 1].w};
      f16x8 hh;
#pragma unroll
      for (int j = 0; j < 8; ++j) {
        nsum = nsum + v[j] * v[j];
        hh[j] = (_Float16)(v[j] * ESCALE);
      }
      *(f16x8*)&Bh[base + (size_t)(u ^ perm) * 8] = hh;
    }
    sNP[kc][rl] = nsum;
    __syncthreads();
    if (t < 32) {
      float s = 0.f;
#pragma unroll
      for (int kc2 = 0; kc2 < 8; ++kc2) s += sNP[kc2][t];
      eNorm[be * 32 + t] = s;
    }
  }
}

// ---------- main: R27 — R25 geometry (64 rows x 128 cols/wave, 2-wave blocks,
// direct-L2, zero LDS/barriers, VGPR 116 no-spill) with a PAIR epilogue:
// top-2-of-8 network + 4-round sorted-PAIR DPP merge (68 vs 99 VALU ops/iter).
// Soundness: k2-in-window triggers a 128-col tile rescan in k_post (k2 is a
// GUARD, never a candidate-only — R16 lesson).
__global__ __launch_bounds__(128, 2) void k_scores_mfma(
    const _Float16* __restrict__ Ah, const _Float16* __restrict__ Bh,
    const float* __restrict__ eNorm,
    unsigned* __restrict__ pK1, unsigned* __restrict__ pK2) {
#pragma clang fp contract(off)
  const int mt = blockIdx.x, nt = blockIdx.y;
  const int m0 = mt * 128, n0 = nt * 128;

  const int t = threadIdx.x;
  const int lane = t & 63, w = t >> 6;        // 2 waves
  const int tx = lane & 15, quad = lane >> 4;
  const int wm = w * 64;                      // wave rows [wm, wm+64), cols [0,128)
  const int swz = (quad ^ ((tx >> 1) & 3)) * 8;  // physical f16 offset of logical block

  const size_t planeA = (size_t)N_ROWS * 32, planeB = (size_t)N_E * 32;
  const size_t baseA = (size_t)(m0 + wm + tx) * 32 + swz;   // f16 index
  const size_t baseB = (size_t)(n0 + tx) * 32 + swz;

  f32x4 acc[4][8];
#pragma unroll
  for (int i = 0; i < 4; ++i)
#pragma unroll
    for (int j = 0; j < 8; ++j) acc[i][j] = (f32x4){0.f, 0.f, 0.f, 0.f};

#pragma unroll
  for (int kc = 0; kc < 8; ++kc) {
    f16x8 ah[4], bh[8];
#pragma unroll
    for (int i = 0; i < 4; ++i)
      ah[i] = *(const f16x8*)&Ah[kc * planeA + baseA + (size_t)i * 512];
#pragma unroll
    for (int j = 0; j < 8; ++j)
      bh[j] = *(const f16x8*)&Bh[kc * planeB + baseB + (size_t)j * 512];

    __builtin_amdgcn_s_setprio(1);
#pragma unroll
    for (int j = 0; j < 8; ++j)
#pragma unroll
      for (int i = 0; i < 4; ++i)
        acc[i][j] = __builtin_amdgcn_mfma_f32_16x16x32_f16(ah[i], bh[j], acc[i][j], 0, 0, 0);
    __builtin_amdgcn_s_setprio(0);
  }

  // ---- epilogue: packed-key top-2 per (row, 128-col tile), pair DPP merge ----
  // eNq in registers (same fmaf as before -> bit-identical keys)
  float enq[8];
#pragma unroll
  for (int j = 0; j < 8; ++j)
    enq[j] = fmaf(eNorm[n0 + j * 16 + tx], 2097152.f, 131072.f);

#pragma unroll
  for (int i = 0; i < 4; ++i) {
#pragma unroll
    for (int r = 0; r < 4; ++r) {
      const int rloc = wm + i * 16 + quad * 4 + r;
      unsigned k[8];
#pragma unroll
      for (int j = 0; j < 8; ++j) {
        float tq = fmaf(acc[i][j][r], -4.0f, enq[j]);   // (s - SMIN)*2^21
        k[j] = (((unsigned)tq) << 14) | (unsigned)(n0 + j * 16 + tx);
      }
      // per-lane top-2 of 8: pairwise mins/maxs + pair-merge tree
      unsigned a = min(k[0], k[1]), b = max(k[0], k[1]);
      unsigned c = min(k[2], k[3]), d = max(k[2], k[3]);
      unsigned e = min(k[4], k[5]), f = max(k[4], k[5]);
      unsigned g = min(k[6], k[7]), h = max(k[6], k[7]);
      unsigned p1 = min(a, c), p2 = min(max(a, c), min(b, d));
      unsigned q1 = min(e, g), q2 = min(max(e, g), min(f, h));
      unsigned m1 = min(p1, q1), m2 = min(max(p1, q1), min(p2, q2));
      // 4-round row_ror DPP merge of sorted pairs (windows partition exactly)
#define MERGE_P(CTRL)                                              \
      {                                                            \
        unsigned o1 = ROR_DPP(m1, CTRL);                           \
        unsigned o2 = ROR_DPP(m2, CTRL);                           \
        unsigned n1 = min(m1, o1);                                 \
        unsigned n2 = min(max(m1, o1), min(m2, o2));               \
        m1 = n1; m2 = n2;                                          \
      }
      MERGE_P(0x121)   // ror:1
      MERGE_P(0x122)   // ror:2
      MERGE_P(0x124)   // ror:4
      MERGE_P(0x128)   // ror:8
#undef MERGE_P
      if (tx == 0) {
        const size_t o = (size_t)nt * N_ROWS + m0 + rloc;
        pK1[o] = m1;
        pK2[o] = m2;
      }
    }
  }
}

// ---------- fused post: key window; k1 -> candidate, k2 -> tile rescan guard ----------
__global__ __launch_bounds__(1024) void k_post(
    const unsigned* __restrict__ pK1, const unsigned* __restrict__ pK2,
    const float* __restrict__ zL1, const float* __restrict__ zNorm,
    const float* __restrict__ z, const float* __restrict__ E,
    const float* __restrict__ eNorm,
    float* __restrict__ out, float* __restrict__ out_loss,
    float* __restrict__ out_idx) {
#pragma clang fp contract(off)
  __shared__ float zc[32][264];     // z rows cache (+pad)
  __shared__ unsigned sM[32][32];   // [s][r]
  __shared__ unsigned gK[32];
  __shared__ int   fI[32];
  __shared__ int   cand[32][16];
  __shared__ int   ccnt[32];
  __shared__ int   heavy[32][4];
  __shared__ int   hcnt[32];
  __shared__ float fS[32][32];      // [r][s]
  __shared__ int   fiS[32][32];
  __shared__ float wsum[16];

  const int t = threadIdx.x;
  const int r = t & 31, s = t >> 5;   // s in [0,32)
  const int n0 = blockIdx.x * 32;
  const int n = n0 + r;
  const int b = n >> 10, hw = n & 1023;

  if (t < 32) { ccnt[t] = 0; hcnt[t] = 0; }

  // cache this row's z: thread owns channels [s*8, s*8+8)
  {
    const float* zrow = z + ((size_t)b * E_DIM + s * 8) * HW + hw;
#pragma unroll
    for (int k = 0; k < 8; ++k) zc[r][s * 8 + k] = zrow[(size_t)k * HW];
  }

  // (A) global approx min over 128 tiles: 4 per s-thread
  unsigned mk = 0xFFFFFFFFu;
#pragma unroll
  for (int i = 0; i < 4; ++i) {
    int ti = s * 4 + i;
    mk = min(mk, pK1[(size_t)ti * N_ROWS + n]);
  }
  sM[s][r] = mk;
  __syncthreads();
  if (t < 32) {
    unsigned bk = sM[0][t];
#pragma unroll
    for (int s3 = 1; s3 < 32; ++s3) bk = min(bk, sM[s3][t]);
    gK[t] = bk;
  }
  __syncthreads();

  // (B) window in key space: W = 2^-22*||z||_1 + 8e-5, +3 quant steps slack.
  // k1 in window -> direct candidate (idx packed); k2 in window -> tile rescan.
  {
    const unsigned qW =
        (unsigned)(fmaf(zL1[n], 2.384185791015625e-7f, 8e-5f) * 2097152.f) + 3u;
    unsigned thrq = (gK[r] >> 14) + qW;
    if (thrq > 262143u) thrq = 262143u;
    const unsigned thrk = (thrq << 14) | 0x3FFFu;
#pragma unroll
    for (int i = 0; i < 4; ++i) {
      int ti = s * 4 + i;
      size_t o = (size_t)ti * N_ROWS + n;
      unsigned k1 = pK1[o], k2 = pK2[o];
      if (k1 <= thrk) { int p = atomicAdd(&ccnt[r], 1); if (p < 16) cand[r][p] = (int)(k1 & 0x3FFFu); }
      if (k2 <= thrk) { int p = atomicAdd(&hcnt[r], 1); if (p < 4)  heavy[r][p] = ti; }
    }
  }
  __syncthreads();

  // (C) f32 reference rescore of window members; lexicographic (s_p, idx) min
  {
    const int rcnt = ccnt[r], rhc = hcnt[r];
    const bool ovf = (rcnt > 16) || (rhc > 4);
    const bool ex = (rcnt > 1) || (rhc > 0);
    float bv = 3.4e38f;
    int bi = 0x7fffffff;
    if (ex) {
      const float zn = zNorm[n];
      if (ovf) {
        for (int k = s; k < N_E; k += 32) {
          float sp = score_ref32(&zc[r][0], E, eNorm, k, zn);
          if (sp < bv || (sp == bv && k < bi)) { bv = sp; bi = k; }
        }
      } else {
        for (int c = s; c < rcnt; c += 32) {
          int idx = cand[r][c];
          float sp = score_ref32(&zc[r][0], E, eNorm, idx, zn);
          if (sp < bv || (sp == bv && idx < bi)) { bv = sp; bi = idx; }
        }
        for (int h = 0; h < rhc; ++h) {
          int ti = heavy[r][h];
          for (int cc = s; cc < 128; cc += 32) {
            int idx = ti * 128 + cc;
            float sp = score_ref32(&zc[r][0], E, eNorm, idx, zn);
            if (sp < bv || (sp == bv && idx < bi)) { bv = sp; bi = idx; }
          }
        }
      }
    }
    fS[r][s] = bv;
    fiS[r][s] = bi;
  }
  __syncthreads();
  if (t < 32) {
    const int rcnt = ccnt[t], rhc = hcnt[t];
    int fidx;
    if (rcnt <= 1 && rhc == 0) {
      fidx = (int)(gK[t] & 0x3FFFu);   // sole window member == unique f32 argmin
    } else {
      float bv = fS[t][0];
      int bi = fiS[t][0];
#pragma unroll
      for (int s3 = 1; s3 < 32; ++s3) {
        float v = fS[t][s3];
        int id = fiS[t][s3];
        if (v < bv || (v == bv && id < bi)) { bv = v; bi = id; }
      }
      fidx = bi;
    }
    fI[t] = fidx;
    out_idx[n0 + t] = (float)fidx;
  }
  __syncthreads();

  // (D) gather + write + loss: thread owns 8 channels [s*8, s*8+8)
  const int idx = fI[r];
  const float4* erow4 = (const float4*)(E + (size_t)idx * E_DIM + s * 8);
  float* orow = out + ((size_t)b * E_DIM + s * 8) * HW + hw;
  float acc = 0.f;
#pragma unroll
  for (int c4 = 0; c4 < 2; ++c4) {
    float4 e4 = erow4[c4];
    float ev[4] = {e4.x, e4.y, e4.z, e4.w};
#pragma unroll
    for (int j2 = 0; j2 < 4; ++j2) {
      int c = c4 * 4 + j2;
      float zv = zc[r][s * 8 + c];
      orow[(size_t)c * HW] = ev[j2];
      float d = ev[j2] - zv;
      acc = fmaf(d, d, acc);
    }
  }
  for (int off = 32; off > 0; off >>= 1) acc += __shfl_down(acc, off, 64);
  if ((t & 63) == 0) wsum[t >> 6] = acc;
  __syncthreads();
  if (t == 0) {
    float s0 = 0.f;
#pragma unroll
    for (int wv = 0; wv < 16; ++wv) s0 += wsum[wv];
    atomicAdd(out_loss, s0 * (1.25f / 2097152.f));
  }
}

extern "C" void kernel_launch(void* const* d_in, const int* in_sizes, int n_in,
                              void* d_out, int out_size, void* d_ws, size_t ws_size,
                              hipStream_t stream) {
  const float* z = (const float*)d_in[0];
  const float* E = (const float*)d_in[1];
  float* out = (float*)d_out;
  float* out_loss = out + 2097152;  // after z_q (8*256*32*32)
  float* out_idx = out + 2097153;

  // workspace (~20 MB): Ah f16[8][8192][32], Bh f16[8][16384][32],
  //                     eNorm, zL1, zNorm, pK1|pK2 u32[128][8192]
  _Float16* Ah = (_Float16*)d_ws;
  _Float16* Bh = Ah + (size_t)N_ROWS * E_DIM;
  float* eNorm = (float*)(Bh + (size_t)N_E * E_DIM);
  float* zL1 = eNorm + N_E;
  float* zNorm = zL1 + N_ROWS;
  unsigned* pK1 = (unsigned*)(zNorm + N_ROWS);
  unsigned* pK2 = pK1 + (size_t)NPART * N_ROWS;

  k_prep<<<ZB_Z + EB_E, 256, 0, stream>>>(z, E, Ah, Bh, eNorm, zNorm, zL1, out_loss);
  k_scores_mfma<<<dim3(N_ROWS / 128, N_E / 128), 128, 0, stream>>>(
      Ah, Bh, eNorm, pK1, pK2);
  k_post<<<N_ROWS / 32, 1024, 0, stream>>>(
      pK1, pK2, zL1, zNorm, z, E, eNorm, out, out_loss, out_idx);
}

// Round 16
// 174.799 us; speedup vs baseline: 4.5211x; 1.1234x over previous
//
#include <hip/hip_runtime.h>

#define E_DIM  256
#define N_E    16384
#define N_ROWS 8192
#define HW     1024
#define NPART  128          // n-tiles of 128 cols

typedef _Float16 f16x8 __attribute__((ext_vector_type(8)));
typedef float    f32x4 __attribute__((ext_vector_type(4)));

#define ESCALE   1048576.0f          // 2^20 (exact)
#define UNSCALE  1.9073486328125e-6f // 2^-19: acc*2^-19 == 2*dot (approx, single limb)

// merge two sorted triples -> top-3 (9 min/max ops)
#define MERGE3(m1, m2, m3, t1, t2, t3)                       \
  {                                                          \
    unsigned n1 = min(m1, t1);                               \
    unsigned n2 = min(max(m1, t1), min(m2, t2));             \
    unsigned n3 = min(min(m3, t3), min(max(m2, t1), max(m1, t2))); \
    m1 = n1; m2 = n2; m3 = n3;                               \
  }

// reference-semantics f32 score: fl32(fl32(zn+en) - fl32(2*dot)).
// All dot intermediates are ~1e-4 scale (|e|<6.1e-5): f32 sum error ~1e-9 <<
// final-subtraction ulp 3e-5 -> same f32 bucket as numpy's einsum.
__device__ __forceinline__ float score_ref32(const float* zr,
                                             const float* __restrict__ E,
                                             const float* __restrict__ eNorm,
                                             int idx, float zn) {
  const float4* e4p = (const float4*)(E + (size_t)idx * E_DIM);
  float d0 = 0.f, d1 = 0.f, d2 = 0.f, d3 = 0.f;
#pragma unroll 16
  for (int q = 0; q < 64; ++q) {
    float4 e4 = e4p[q];
    d0 = fmaf(zr[q * 4 + 0], e4.x, d0);
    d1 = fmaf(zr[q * 4 + 1], e4.y, d1);
    d2 = fmaf(zr[q * 4 + 2], e4.z, d2);
    d3 = fmaf(zr[q * 4 + 3], e4.w, d3);
  }
  float dot = (d0 + d1) + (d2 + d3);
  float base = zn + eNorm[idx];   // f32 add, matches np broadcast add
  float td = 2.0f * dot;          // exact (power of 2)
  return base - td;               // f32 final rounding at the reference ulp
}

// ---------- fused prep: single-limb A/B + eNorm + numpy-exact zNorm + z L1 ----------
#define ZB_Z    256
#define EB_E    512
__global__ __launch_bounds__(256) void k_prep(const float* __restrict__ z,
                                              const float* __restrict__ E,
                                              _Float16* __restrict__ Ah,
                                              _Float16* __restrict__ Bh,
                                              float* __restrict__ eNorm,
                                              float* __restrict__ zNorm,
                                              float* __restrict__ zL1,
                                              float* __restrict__ out_loss) {
#pragma clang fp contract(off)
  const int bi = blockIdx.x, t = threadIdx.x;

  if (bi < ZB_Z) {
    // ---- z section: 32-row tile ----
    __shared__ float sLZ[256][32];   // 32 KB z tile [channel][row]
    __shared__ float sN2[16][32];    // square-chain partials [c16][row]
    __shared__ float sL1[16][32];    // abs-chain partials
    const int n0 = bi * 32;
    const int b = n0 >> 10, hw0 = n0 & 1023;

    {
      const int nl = t & 31, cs = t >> 5;
      const float* zb = z + (size_t)b * E_DIM * HW + hw0 + nl;
#pragma unroll 4
      for (int it = 0; it < 32; ++it) {
        int c = it * 8 + cs;
        sLZ[c][nl] = zb[(size_t)c * HW];
      }
    }
    __syncthreads();

    // phase L: high limb only. thread = (row nl, segment seg = kc)
    {
      const int nl = t & 31, seg = t >> 5;
      const int n = n0 + nl;
      const int perm = (n >> 1) & 3;
#pragma unroll
      for (int u = 0; u < 4; ++u) {
        const int c0 = seg * 32 + u * 8;
        f16x8 hh;
#pragma unroll
        for (int j = 0; j < 8; ++j) hh[j] = (_Float16)sLZ[c0 + j][nl];
        size_t dst = (size_t)seg * (N_ROWS * 32) + (size_t)n * 32 + (size_t)(u ^ perm) * 8;
        *(f16x8*)&Ah[dst] = hh;
      }
    }

    // phase N: numpy-exact square chains (zNorm) + abs chains (zL1 window scale)
#pragma unroll
    for (int it = 0; it < 2; ++it) {
      int task = it * 256 + t;
      int nl = task & 31, c16 = task >> 5;
      int h = c16 >> 3, j = c16 & 7;
      float r2 = 0.f, r1 = 0.f;
#pragma unroll
      for (int i = 0; i < 16; ++i) {
        float v = sLZ[h * 128 + i * 8 + j][nl];
        r2 = r2 + v * v;
        r1 = r1 + fabsf(v);
      }
      sN2[c16][nl] = r2;
      sL1[c16][nl] = r1;
    }
    __syncthreads();
    if (t < 32) {
      float q[16], p[16];
#pragma unroll
      for (int c16 = 0; c16 < 16; ++c16) { q[c16] = sN2[c16][t]; p[c16] = sL1[c16][t]; }
      float h0 = ((q[0] + q[1]) + (q[2] + q[3])) + ((q[4] + q[5]) + (q[6] + q[7]));
      float h1 = ((q[8] + q[9]) + (q[10] + q[11])) + ((q[12] + q[13]) + (q[14] + q[15]));
      zNorm[n0 + t] = h0 + h1;
      float g0 = ((p[0] + p[1]) + (p[2] + p[3])) + ((p[4] + p[5]) + (p[6] + p[7]));
      float g1 = ((p[8] + p[9]) + (p[10] + p[11])) + ((p[12] + p[13]) + (p[14] + p[15]));
      zL1[n0 + t] = g0 + g1;
    }
  } else {
    // ---- E section ----
    __shared__ float sNP[8][32];
    const int be = bi - ZB_Z;
    if (be == 0 && t == 0) out_loss[0] = 0.f;
    const int kc = t >> 5, rl = t & 31;
    const int k = be * 32 + rl;
    const int perm = (k >> 1) & 3;
    const float* src = E + (size_t)k * E_DIM + kc * 32;

    float4 v4[8];
#pragma unroll
    for (int u2 = 0; u2 < 8; ++u2) v4[u2] = ((const float4*)src)[u2];

    float nsum = 0.f;
    size_t base = (size_t)kc * (N_E * 32) + (size_t)k * 32;
#pragma unroll
    for (int u = 0; u < 4; ++u) {
      float v[8] = {v4[u * 2].x, v4[u * 2].y, v4[u * 2].z, v4[u * 2].w,
                    v4[u * 2 + 1].x, v4[u * 2 + 1].y, v4[u * 2 + 1].z, v4[u * 2 + 1].w};
      f16x8 hh;
#pragma unroll
      for (int j = 0; j < 8; ++j) {
        nsum = nsum + v[j] * v[j];
        hh[j] = (_Float16)(v[j] * ESCALE);
      }
      *(f16x8*)&Bh[base + (size_t)(u ^ perm) * 8] = hh;
    }
    sNP[kc][rl] = nsum;
    __syncthreads();
    if (t < 32) {
      float s = 0.f;
#pragma unroll
      for (int kc2 = 0; kc2 < 8; ++kc2) s += sNP[kc2][t];
      eNorm[be * 32 + t] = s;
    }
  }
}

// ---------- main: R28 — R25 geometry (64 rows x 128 cols/wave, 2-wave blocks,
// direct-L2, zero LDS/barriers) with SWAPPED MFMA operands: mfma(bh, ah) gives
// C[e-col][z-row] -> each lane holds 32 e-cols of ONE row in registers (quads
// partition the 128 cols). Top-3 is lane-local (no 16-lane SIMD replication);
// only 2 cross-quad shfl_xor rounds (idle LDS pipe). Dots/keys bit-identical.
__global__ __launch_bounds__(128, 2) void k_scores_mfma(
    const _Float16* __restrict__ Ah, const _Float16* __restrict__ Bh,
    const float* __restrict__ eNorm,
    unsigned* __restrict__ pK1, unsigned* __restrict__ pK2,
    unsigned* __restrict__ pK3) {
#pragma clang fp contract(off)
  const int mt = blockIdx.x, nt = blockIdx.y;
  const int m0 = mt * 128, n0 = nt * 128;

  const int t = threadIdx.x;
  const int lane = t & 63, w = t >> 6;        // 2 waves
  const int tx = lane & 15, quad = lane >> 4;
  const int wm = w * 64;                      // wave rows [wm, wm+64), cols [0,128)
  const int swz = (quad ^ ((tx >> 1) & 3)) * 8;  // physical f16 offset of logical block

  const size_t planeA = (size_t)N_ROWS * 32, planeB = (size_t)N_E * 32;
  const size_t baseA = (size_t)(m0 + wm + tx) * 32 + swz;   // f16 index
  const size_t baseB = (size_t)(n0 + tx) * 32 + swz;

  f32x4 acc[4][8];
#pragma unroll
  for (int i = 0; i < 4; ++i)
#pragma unroll
    for (int j = 0; j < 8; ++j) acc[i][j] = (f32x4){0.f, 0.f, 0.f, 0.f};

#pragma unroll
  for (int kc = 0; kc < 8; ++kc) {
    f16x8 ah[4], bh[8];
#pragma unroll
    for (int i = 0; i < 4; ++i)
      ah[i] = *(const f16x8*)&Ah[kc * planeA + baseA + (size_t)i * 512];
#pragma unroll
    for (int j = 0; j < 8; ++j)
      bh[j] = *(const f16x8*)&Bh[kc * planeB + baseB + (size_t)j * 512];

    __builtin_amdgcn_s_setprio(1);
#pragma unroll
    for (int j = 0; j < 8; ++j)
#pragma unroll
      for (int i = 0; i < 4; ++i)
        acc[i][j] = __builtin_amdgcn_mfma_f32_16x16x32_f16(bh[j], ah[i], acc[i][j], 0, 0, 0);
    __builtin_amdgcn_s_setprio(0);
  }

  // ---- epilogue: lane-local top-3 over 32 cols/row + 2 cross-quad merges ----
  // acc[i][j][r] = score-dot for row (m0+wm+i*16+tx), col (n0+j*16+quad*4+r)
  const unsigned colb = (unsigned)(n0 + quad * 4);
#pragma unroll
  for (int i = 0; i < 4; ++i) {
    unsigned m1 = 0xFFFFFFFFu, m2 = 0xFFFFFFFFu, m3 = 0xFFFFFFFFu;
#pragma unroll
    for (int j = 0; j < 8; ++j) {
      // eNorm for cols j*16+quad*4 .. +3 (float4, L1-hot across i)
      float4 e4 = ((const float4*)(eNorm + n0 + j * 16))[quad];
      unsigned kk[4];
      {
        float q0 = fmaf(e4.x, 2097152.f, 131072.f);
        float q1 = fmaf(e4.y, 2097152.f, 131072.f);
        float q2 = fmaf(e4.z, 2097152.f, 131072.f);
        float q3 = fmaf(e4.w, 2097152.f, 131072.f);
        kk[0] = (((unsigned)fmaf(acc[i][j][0], -4.0f, q0)) << 14) | (colb + j * 16 + 0);
        kk[1] = (((unsigned)fmaf(acc[i][j][1], -4.0f, q1)) << 14) | (colb + j * 16 + 1);
        kk[2] = (((unsigned)fmaf(acc[i][j][2], -4.0f, q2)) << 14) | (colb + j * 16 + 2);
        kk[3] = (((unsigned)fmaf(acc[i][j][3], -4.0f, q3)) << 14) | (colb + j * 16 + 3);
      }
      // top-3 of 4
      unsigned a = min(kk[0], kk[1]), b = max(kk[0], kk[1]);
      unsigned c = min(kk[2], kk[3]), d = max(kk[2], kk[3]);
      unsigned t1 = min(a, c), e0 = max(a, c), f0 = min(b, d);
      unsigned t2 = min(e0, f0), t3 = max(e0, f0);
      MERGE3(m1, m2, m3, t1, t2, t3)
    }
    // cross-quad: q ^ 1 (lane^16), then q ^ 2 (lane^32) — LDS pipe (idle)
    {
      unsigned o1 = (unsigned)__shfl_xor((int)m1, 16, 64);
      unsigned o2 = (unsigned)__shfl_xor((int)m2, 16, 64);
      unsigned o3 = (unsigned)__shfl_xor((int)m3, 16, 64);
      MERGE3(m1, m2, m3, o1, o2, o3)
      o1 = (unsigned)__shfl_xor((int)m1, 32, 64);
      o2 = (unsigned)__shfl_xor((int)m2, 32, 64);
      o3 = (unsigned)__shfl_xor((int)m3, 32, 64);
      MERGE3(m1, m2, m3, o1, o2, o3)
    }
    if (quad == 0) {   // 16 consecutive rows -> coalesced 64B stores
      const size_t o = (size_t)nt * N_ROWS + m0 + wm + i * 16 + tx;
      pK1[o] = m1;
      pK2[o] = m2;
      pK3[o] = m3;
    }
  }
}

// ---------- fused post: R23/R25 (1024 threads, top-3 window) — verbatim ----------
__global__ __launch_bounds__(1024) void k_post(
    const unsigned* __restrict__ pK1, const unsigned* __restrict__ pK2,
    const unsigned* __restrict__ pK3,
    const float* __restrict__ zL1, const float* __restrict__ zNorm,
    const float* __restrict__ z, const float* __restrict__ E,
    const float* __restrict__ eNorm,
    float* __restrict__ out, float* __restrict__ out_loss,
    float* __restrict__ out_idx) {
#pragma clang fp contract(off)
  __shared__ float zc[32][264];     // z rows cache (+pad)
  __shared__ unsigned sM[32][32];   // [s][r]
  __shared__ unsigned gK[32];
  __shared__ int   fI[32];
  __shared__ int   cand[32][16];
  __shared__ int   ccnt[32];
  __shared__ int   heavy[32][4];
  __shared__ int   hcnt[32];
  __shared__ float fS[32][32];      // [r][s]
  __shared__ int   fiS[32][32];
  __shared__ float wsum[16];

  const int t = threadIdx.x;
  const int r = t & 31, s = t >> 5;   // s in [0,32)
  const int n0 = blockIdx.x * 32;
  const int n = n0 + r;
  const int b = n >> 10, hw = n & 1023;

  if (t < 32) { ccnt[t] = 0; hcnt[t] = 0; }

  // cache this row's z: thread owns channels [s*8, s*8+8)
  {
    const float* zrow = z + ((size_t)b * E_DIM + s * 8) * HW + hw;
#pragma unroll
    for (int k = 0; k < 8; ++k) zc[r][s * 8 + k] = zrow[(size_t)k * HW];
  }

  // (A) global approx min over 128 tiles: 4 per s-thread
  unsigned mk = 0xFFFFFFFFu;
#pragma unroll
  for (int i = 0; i < 4; ++i) {
    int ti = s * 4 + i;
    mk = min(mk, pK1[(size_t)ti * N_ROWS + n]);
  }
  sM[s][r] = mk;
  __syncthreads();
  if (t < 32) {
    unsigned bk = sM[0][t];
#pragma unroll
    for (int s3 = 1; s3 < 32; ++s3) bk = min(bk, sM[s3][t]);
    gK[t] = bk;
  }
  __syncthreads();

  // (B) window in key space: W = 2^-22*||z||_1 + 8e-5, +3 quant steps slack.
  // k1,k2 in window -> direct candidates (idx packed); k3 in window -> heavy.
  {
    const unsigned qW =
        (unsigned)(fmaf(zL1[n], 2.384185791015625e-7f, 8e-5f) * 2097152.f) + 3u;
    unsigned thrq = (gK[r] >> 14) + qW;
    if (thrq > 262143u) thrq = 262143u;
    const unsigned thrk = (thrq << 14) | 0x3FFFu;
#pragma unroll
    for (int i = 0; i < 4; ++i) {
      int ti = s * 4 + i;
      size_t o = (size_t)ti * N_ROWS + n;
      unsigned k1 = pK1[o], k2 = pK2[o], k3 = pK3[o];
      if (k1 <= thrk) { int p = atomicAdd(&ccnt[r], 1); if (p < 16) cand[r][p] = (int)(k1 & 0x3FFFu); }
      if (k2 <= thrk) { int p = atomicAdd(&ccnt[r], 1); if (p < 16) cand[r][p] = (int)(k2 & 0x3FFFu); }
      if (k3 <= thrk) { int p = atomicAdd(&hcnt[r], 1); if (p < 4)  heavy[r][p] = ti; }
    }
  }
  __syncthreads();

  // (C) f32 reference rescore of window members; lexicographic (s_p, idx) min
  {
    const int rcnt = ccnt[r], rhc = hcnt[r];
    const bool ovf = (rcnt > 16) || (rhc > 4);
    const bool ex = (rcnt > 1) || (rhc > 0);
    float bv = 3.4e38f;
    int bi = 0x7fffffff;
    if (ex) {
      const float zn = zNorm[n];
      if (ovf) {
        for (int k = s; k < N_E; k += 32) {
          float sp = score_ref32(&zc[r][0], E, eNorm, k, zn);
          if (sp < bv || (sp == bv && k < bi)) { bv = sp; bi = k; }
        }
      } else {
        for (int c = s; c < rcnt; c += 32) {
          int idx = cand[r][c];
          float sp = score_ref32(&zc[r][0], E, eNorm, idx, zn);
          if (sp < bv || (sp == bv && idx < bi)) { bv = sp; bi = idx; }
        }
        for (int h = 0; h < rhc; ++h) {
          int ti = heavy[r][h];
          for (int cc = s; cc < 128; cc += 32) {
            int idx = ti * 128 + cc;
            float sp = score_ref32(&zc[r][0], E, eNorm, idx, zn);
            if (sp < bv || (sp == bv && idx < bi)) { bv = sp; bi = idx; }
          }
        }
      }
    }
    fS[r][s] = bv;
    fiS[r][s] = bi;
  }
  __syncthreads();
  if (t < 32) {
    const int rcnt = ccnt[t], rhc = hcnt[t];
    int fidx;
    if (rcnt <= 1 && rhc == 0) {
      fidx = (int)(gK[t] & 0x3FFFu);   // sole window member == unique f32 argmin
    } else {
      float bv = fS[t][0];
      int bi = fiS[t][0];
#pragma unroll
      for (int s3 = 1; s3 < 32; ++s3) {
        float v = fS[t][s3];
        int id = fiS[t][s3];
        if (v < bv || (v == bv && id < bi)) { bv = v; bi = id; }
      }
      fidx = bi;
    }
    fI[t] = fidx;
    out_idx[n0 + t] = (float)fidx;
  }
  __syncthreads();

  // (D) gather + write + loss: thread owns 8 channels [s*8, s*8+8)
  const int idx = fI[r];
  const float4* erow4 = (const float4*)(E + (size_t)idx * E_DIM + s * 8);
  float* orow = out + ((size_t)b * E_DIM + s * 8) * HW + hw;
  float acc = 0.f;
#pragma unroll
  for (int c4 = 0; c4 < 2; ++c4) {
    float4 e4 = erow4[c4];
    float ev[4] = {e4.x, e4.y, e4.z, e4.w};
#pragma unroll
    for (int j2 = 0; j2 < 4; ++j2) {
      int c = c4 * 4 + j2;
      float zv = zc[r][s * 8 + c];
      orow[(size_t)c * HW] = ev[j2];
      float d = ev[j2] - zv;
      acc = fmaf(d, d, acc);
    }
  }
  for (int off = 32; off > 0; off >>= 1) acc += __shfl_down(acc, off, 64);
  if ((t & 63) == 0) wsum[t >> 6] = acc;
  __syncthreads();
  if (t == 0) {
    float s0 = 0.f;
#pragma unroll
    for (int wv = 0; wv < 16; ++wv) s0 += wsum[wv];
    atomicAdd(out_loss, s0 * (1.25f / 2097152.f));
  }
}

extern "C" void kernel_launch(void* const* d_in, const int* in_sizes, int n_in,
                              void* d_out, int out_size, void* d_ws, size_t ws_size,
                              hipStream_t stream) {
  const float* z = (const float*)d_in[0];
  const float* E = (const float*)d_in[1];
  float* out = (float*)d_out;
  float* out_loss = out + 2097152;  // after z_q (8*256*32*32)
  float* out_idx = out + 2097153;

  // workspace (~25 MB): Ah f16[8][8192][32], Bh f16[8][16384][32],
  //                     eNorm, zL1, zNorm, pK1|pK2|pK3 u32[128][8192]
  _Float16* Ah = (_Float16*)d_ws;
  _Float16* Bh = Ah + (size_t)N_ROWS * E_DIM;
  float* eNorm = (float*)(Bh + (size_t)N_E * E_DIM);
  float* zL1 = eNorm + N_E;
  float* zNorm = zL1 + N_ROWS;
  unsigned* pK1 = (unsigned*)(zNorm + N_ROWS);
  unsigned* pK2 = pK1 + (size_t)NPART * N_ROWS;
  unsigned* pK3 = pK2 + (size_t)NPART * N_ROWS;

  k_prep<<<ZB_Z + EB_E, 256, 0, stream>>>(z, E, Ah, Bh, eNorm, zNorm, zL1, out_loss);
  k_scores_mfma<<<dim3(N_ROWS / 128, N_E / 128), 128, 0, stream>>>(
      Ah, Bh, eNorm, pK1, pK2, pK3);
  k_post<<<N_ROWS / 32, 1024, 0, stream>>>(
      pK1, pK2, pK3, zL1, zNorm, z, E, eNorm, out, out_loss, out_idx);
}